// Round 5
// baseline (3395.382 us; speedup 1.0000x reference)
//
#include <hip/hip_runtime.h>

typedef unsigned int u32;
typedef unsigned short u16;
typedef _Float16 f16;
typedef f16 f16x8 __attribute__((ext_vector_type(8)));
typedef float f32x4 __attribute__((ext_vector_type(4)));
typedef u16 u16x8 __attribute__((ext_vector_type(8)));

#define DIM 1024
#define BATCH 32768
#define RANK 32
#define NLIN 18

__device__ __forceinline__ u16 f2h(float f) {
    f16 h = (f16)f;
    return *(u16*)&h;
}
__device__ __forceinline__ float h2f(u16 u) {
    f16 h;
    *(u16*)&h = u;
    return (float)h;
}

__device__ __forceinline__ void gload16(const u16* g, u16* l) {
    __builtin_amdgcn_global_load_lds((__attribute__((address_space(1))) const void*)g,
                                     (__attribute__((address_space(3))) void*)l,
                                     16, 0, 0);
}

#define BAR()        __builtin_amdgcn_s_barrier()
#define ASM_VM0()    asm volatile("s_waitcnt vmcnt(0)" ::: "memory")
#define ASM_VM4()    asm volatile("s_waitcnt vmcnt(4)" ::: "memory")
#define ASM_LG0()    asm volatile("s_waitcnt lgkmcnt(0)" ::: "memory")
#define ASM_LG4()    asm volatile("s_waitcnt lgkmcnt(4)" ::: "memory")
#define ASM_LG8()    asm volatile("s_waitcnt lgkmcnt(8)" ::: "memory")

// ---- W_eff = dequant(wq, scales) + lb @ la  -> fp16 [NLIN][DIM][DIM] ----
__global__ __launch_bounds__(256) void build_weff(
    const int* __restrict__ wq, const float* __restrict__ scales,
    const float* __restrict__ la, const float* __restrict__ lb,
    u16* __restrict__ weff)
{
    int rb = blockIdx.x;   // 0..63, 16 rows each
    int li = blockIdx.y;   // 0..17
    int tid = threadIdx.x;
    int row0 = rb * 16;
    __shared__ float lb_s[16][RANK];
    __shared__ float la_s[RANK][256];
    for (int idx = tid; idx < 16 * RANK; idx += 256) {
        int o = idx >> 5, r = idx & 31;
        lb_s[o][r] = lb[((size_t)li * DIM + row0 + o) * RANK + r];
    }
    const int* wqL = wq + (size_t)li * DIM * DIM;
    const float* sL = scales + (size_t)li * (DIM * DIM / 16);
    u16* wout = weff + (size_t)li * DIM * DIM;
    for (int kc = 0; kc < DIM; kc += 256) {
        __syncthreads();
        #pragma unroll
        for (int j = 0; j < 32; ++j) {
            int idx = j * 256 + tid;
            int r = idx >> 8, c = idx & 255;
            la_s[r][c] = la[((size_t)li * RANK + r) * DIM + kc + c];
        }
        __syncthreads();
        int k = kc + tid;
        for (int o = 0; o < 16; ++o) {
            int og = row0 + o;
            float acc = ((float)wqL[og * DIM + k] - 8.0f) * sL[(og << 6) + (k >> 4)];
            #pragma unroll
            for (int r = 0; r < RANK; ++r)
                acc += lb_s[o][r] * la_s[r][tid];
            wout[og * DIM + k] = f2h(acc);
        }
    }
}

// ---- x fp32 -> fp16 ----
__global__ __launch_bounds__(256) void xcast(const float* __restrict__ x, u16* __restrict__ o) {
    size_t i = ((size_t)blockIdx.x * 256 + threadIdx.x) * 8;
    float4 a = *(const float4*)(x + i);
    float4 b = *(const float4*)(x + i + 4);
    u16x8 v;
    v[0] = f2h(a.x); v[1] = f2h(a.y); v[2] = f2h(a.z); v[3] = f2h(a.w);
    v[4] = f2h(b.x); v[5] = f2h(b.y); v[6] = f2h(b.z); v[7] = f2h(b.w);
    *(u16x8*)(o + i) = v;
}

// ---- 256x256x(BK=64) GEMM, 8 waves (2Mx4N), 4 phases/K-tile.
// Deep pipeline: staging of tile t+2 at ph2(B)/ph3(A) of tile t (counted
// vmcnt(4) placed BEFORE the phase-end barrier => all waves' staging visible
// after it); LDS->reg fragment reads issued ONE PHASE EARLY and guarded by
// counted lgkmcnt(4/8) so ds_read latency hides under the MFMA cluster.
// Frag double-sets: afH0/afH1 per A-half; bf0/bf1 per tile parity (static
// indexing via 2x tile unroll). Swizzle & epilogue as round 4.
// EPI: 0 = relu(acc+bias)->fp16 ; 1 = acc+bias+res->fp16 ; 2 = acc+bias+res->fp32
template<int EPI>
__global__ __launch_bounds__(512, 2) void gemm256(
    const u16* __restrict__ X, const u16* __restrict__ W,
    const float* __restrict__ bias, const u16* __restrict__ res,
    void* __restrict__ outp)
{
    __shared__ __align__(16) u16 As[2][256 * 64];
    __shared__ __align__(16) u16 Bs[2][256 * 64];
    const int tid = threadIdx.x;
    const int bid = blockIdx.x;
    // XCD-bijective swizzle: 512 blocks, 8 XCDs, 64 contiguous wg per XCD
    const int wg = (bid & 7) * 64 + (bid >> 3);
    const int bm = wg >> 2;        // 0..127
    const int bn = wg & 3;         // 0..3
    const int wid = tid >> 6;
    const int lane = tid & 63;
    const int wm = wid >> 2;       // 0..1
    const int wn = wid & 3;        // 0..3

    // ---- staging source pointers (global side carries the swizzle) ----
    const int c1 = tid, c2 = tid + 512;           // chunk ids within a 1024-chunk half
    const int r1 = c1 >> 3, r2 = c2 >> 3;         // rows 0..127 within half
    const int l1 = ((c1 & 7) ^ (r1 & 7)) * 8;     // swizzled k-offset (u16)
    const int l2 = ((c2 & 7) ^ (r2 & 7)) * 8;
    const u16* gA0a = X + (size_t)(bm * 256 +       r1) * DIM + l1;
    const u16* gA0b = X + (size_t)(bm * 256 +       r2) * DIM + l2;
    const u16* gA1a = X + (size_t)(bm * 256 + 128 + r1) * DIM + l1;
    const u16* gA1b = X + (size_t)(bm * 256 + 128 + r2) * DIM + l2;
    const u16* gB0a = W + (size_t)(bn * 256 +       r1) * DIM + l1;
    const u16* gB0b = W + (size_t)(bn * 256 +       r2) * DIM + l2;
    const u16* gB1a = W + (size_t)(bn * 256 + 128 + r1) * DIM + l1;
    const u16* gB1b = W + (size_t)(bn * 256 + 128 + r2) * DIM + l2;
    const int d1 = c1 * 8, d2 = c2 * 8;           // linear LDS dest (u16), half adds 8192

    // ---- fragment read offsets ----
    const int kg = lane >> 4;
    const int sw = lane & 7;
    const int ch0 = ((0 * 4 + kg) ^ sw) * 8;      // ks=0 chunk (u16 offset in row)
    const int ch1 = ((1 * 4 + kg) ^ sw) * 8;      // ks=1
    const int aoff = (wm * 128 + (lane & 15)) * 64;
    const int boff = (wn * 64 + (lane & 15)) * 64;

    f32x4 acc[8][4];
    #pragma unroll
    for (int i = 0; i < 8; ++i)
        #pragma unroll
        for (int j = 0; j < 4; ++j)
            acc[i][j] = (f32x4){0.f, 0.f, 0.f, 0.f};
    f16x8 afH0[4][2], afH1[4][2];   // A half-0 / half-1 fragments
    f16x8 bf0[4][2], bf1[4][2];     // B fragments, tile-parity sets

    // ---- prologue: stage tile0 (8 loads), then tile1 (B-group FIRST, then A) ----
    gload16(gA0a, &As[0][d1]);        gload16(gA0b, &As[0][d2]);
    gload16(gA1a, &As[0][8192 + d1]); gload16(gA1b, &As[0][8192 + d2]);
    gload16(gB0a, &Bs[0][d1]);        gload16(gB0b, &Bs[0][d2]);
    gload16(gB1a, &Bs[0][8192 + d1]); gload16(gB1b, &Bs[0][8192 + d2]);
    gload16(gB0a + 64, &Bs[1][d1]);        gload16(gB0b + 64, &Bs[1][d2]);
    gload16(gB1a + 64, &Bs[1][8192 + d1]); gload16(gB1b + 64, &Bs[1][8192 + d2]);
    gload16(gA0a + 64, &As[1][d1]);        gload16(gA0b + 64, &As[1][d2]);
    gload16(gA1a + 64, &As[1][8192 + d1]); gload16(gA1b + 64, &As[1][8192 + d2]);

    #define RD_A(AF, MH, BUF) { \
        _Pragma("unroll") \
        for (int fm = 0; fm < 4; ++fm) { \
            AF[fm][0] = *(const f16x8*)&(BUF)[aoff + ((MH)*64 + fm*16)*64 + ch0]; \
            AF[fm][1] = *(const f16x8*)&(BUF)[aoff + ((MH)*64 + fm*16)*64 + ch1]; \
        } }
    #define RD_B(BF, NH, BUF) { \
        _Pragma("unroll") \
        for (int fn = 0; fn < 2; ++fn) { \
            BF[(NH)*2+fn][0] = *(const f16x8*)&(BUF)[boff + (((NH)*2+fn)*16)*64 + ch0]; \
            BF[(NH)*2+fn][1] = *(const f16x8*)&(BUF)[boff + (((NH)*2+fn)*16)*64 + ch1]; \
        } }
    #define QUAD(MH, NH, AF, BF) { \
        __builtin_amdgcn_s_setprio(1); \
        _Pragma("unroll") \
        for (int ks = 0; ks < 2; ++ks) \
            _Pragma("unroll") \
            for (int fm = 0; fm < 4; ++fm) \
                _Pragma("unroll") \
                for (int fn = 0; fn < 2; ++fn) \
                    acc[(MH)*4+fm][(NH)*2+fn] = __builtin_amdgcn_mfma_f32_16x16x32_f16( \
                        AF[fm][ks], BF[(NH)*2+fn][ks], acc[(MH)*4+fm][(NH)*2+fn], 0, 0, 0); \
        __builtin_amdgcn_s_setprio(0); }

    // wait tile0's 8 loads (tile1's 8 newer stay in flight); make visible
    asm volatile("s_waitcnt vmcnt(8)" ::: "memory");
    BAR();
    // pre-read tile0 ph0 fragments
    RD_A(afH0, 0, (&As[0][0]));
    RD_B(bf0, 0, (&Bs[0][0]));

    // Per tile t (parity PT, current B set BFC, next B set BFN):
    //  ph0: rd B1(t)->BFC[2:3]; lg(4); quad(0,0); bar
    //  ph1: rd A1(t)->afH1;     lg(8); quad(0,1); vm(4)[B(t+1) landed]; bar
    //  ph2: stage B(t+2); rd B0(t+1)->BFN[0:1]; lg(4); quad(1,0);
    //       vm(4)[A(t+1) landed] (t==14: vm(0)); bar
    //  ph3: stage A(t+2); rd A0(t+1)->afH0;     lg(8); quad(1,1); bar
    #define TILE(T, PT, BFC, BFN) { \
        /* ph0 */ \
        RD_B(BFC, 1, (&Bs[PT][0])); \
        ASM_LG4(); \
        QUAD(0, 0, afH0, BFC); \
        BAR(); \
        /* ph1 */ \
        RD_A(afH1, 1, (&As[PT][0])); \
        ASM_LG8(); \
        QUAD(0, 1, afH0, BFC); \
        if ((T) < 15) ASM_VM4(); \
        BAR(); \
        /* ph2 */ \
        if ((T) < 14) { \
            const int ko2 = ((T) + 2) * 64; \
            gload16(gB0a + ko2, &Bs[PT][d1]);        gload16(gB0b + ko2, &Bs[PT][d2]); \
            gload16(gB1a + ko2, &Bs[PT][8192 + d1]); gload16(gB1b + ko2, &Bs[PT][8192 + d2]); \
        } \
        if ((T) < 15) { RD_B(BFN, 0, (&Bs[(PT)^1][0])); ASM_LG4(); } else { ASM_LG0(); } \
        QUAD(1, 0, afH1, BFC); \
        if ((T) < 14) ASM_VM4(); else if ((T) == 14) ASM_VM0(); \
        BAR(); \
        /* ph3 */ \
        if ((T) < 14) { \
            const int ko2 = ((T) + 2) * 64; \
            gload16(gA0a + ko2, &As[PT][d1]);        gload16(gA0b + ko2, &As[PT][d2]); \
            gload16(gA1a + ko2, &As[PT][8192 + d1]); gload16(gA1b + ko2, &As[PT][8192 + d2]); \
        } \
        if ((T) < 15) { RD_A(afH0, 0, (&As[(PT)^1][0])); ASM_LG8(); } else { ASM_LG0(); } \
        QUAD(1, 1, afH1, BFC); \
        BAR(); \
    }

    #pragma unroll 1
    for (int tp = 0; tp < 8; ++tp) {
        const int T0 = tp * 2;
        const int T1 = T0 + 1;
        TILE(T0, 0, bf0, bf1);
        TILE(T1, 1, bf1, bf0);
    }

    // ---- epilogue: LDS transpose -> full-line vector stores ----
    ASM_LG0();
    BAR();                             // all waves done reading As/Bs
    float* blk = (float*)&As[0][0] + wid * 1088;   // [16][68] f32 per wave
    const int mrow = bm * 256 + wm * 128;
    const int ncol = bn * 256 + wn * 64 + (lane & 7) * 8;
    float4 bv0 = *(const float4*)&bias[ncol];
    float4 bv1 = *(const float4*)&bias[ncol + 4];
    #pragma unroll
    for (int fm = 0; fm < 8; ++fm) {
        __builtin_amdgcn_sched_barrier(0);
        #pragma unroll
        for (int fn = 0; fn < 4; ++fn)
            #pragma unroll
            for (int reg = 0; reg < 4; ++reg)
                blk[((lane >> 4) * 4 + reg) * 68 + (lane & 15) + fn * 16] = acc[fm][fn][reg];
        ASM_LG0();
        __builtin_amdgcn_sched_barrier(0);
        #pragma unroll
        for (int pass = 0; pass < 2; ++pass) {
            const float* rp = &blk[(pass * 8 + (lane >> 3)) * 68 + (lane & 7) * 8];
            float4 v0 = *(const float4*)rp;
            float4 v1 = *(const float4*)(rp + 4);
            v0.x += bv0.x; v0.y += bv0.y; v0.z += bv0.z; v0.w += bv0.w;
            v1.x += bv1.x; v1.y += bv1.y; v1.z += bv1.z; v1.w += bv1.w;
            const int m = mrow + fm * 16 + pass * 8 + (lane >> 3);
            const size_t gi = (size_t)m * DIM + ncol;
            if (EPI == 0) {
                u16x8 o;
                o[0] = f2h(fmaxf(v0.x, 0.f)); o[1] = f2h(fmaxf(v0.y, 0.f));
                o[2] = f2h(fmaxf(v0.z, 0.f)); o[3] = f2h(fmaxf(v0.w, 0.f));
                o[4] = f2h(fmaxf(v1.x, 0.f)); o[5] = f2h(fmaxf(v1.y, 0.f));
                o[6] = f2h(fmaxf(v1.z, 0.f)); o[7] = f2h(fmaxf(v1.w, 0.f));
                *(u16x8*)((u16*)outp + gi) = o;
            } else {
                u16x8 rv = *(const u16x8*)(res + gi);
                v0.x += h2f(rv[0]); v0.y += h2f(rv[1]); v0.z += h2f(rv[2]); v0.w += h2f(rv[3]);
                v1.x += h2f(rv[4]); v1.y += h2f(rv[5]); v1.z += h2f(rv[6]); v1.w += h2f(rv[7]);
                if (EPI == 1) {
                    u16x8 o;
                    o[0] = f2h(v0.x); o[1] = f2h(v0.y); o[2] = f2h(v0.z); o[3] = f2h(v0.w);
                    o[4] = f2h(v1.x); o[5] = f2h(v1.y); o[6] = f2h(v1.z); o[7] = f2h(v1.w);
                    *(u16x8*)((u16*)outp + gi) = o;
                } else {
                    *(float4*)((float*)outp + gi) = v0;
                    *(float4*)((float*)outp + gi + 4) = v1;
                }
            }
        }
        ASM_LG0();
    }
    #undef RD_A
    #undef RD_B
    #undef QUAD
    #undef TILE
}

// ---- LayerNorm: fp16 in -> fp16 out, one wave per row ----
__global__ __launch_bounds__(256) void ln_k(const u16* __restrict__ in,
    const float* __restrict__ g, const float* __restrict__ b, u16* __restrict__ out)
{
    int row = blockIdx.x * 4 + (threadIdx.x >> 6);
    int lane = threadIdx.x & 63;
    const u16* rp = in + (size_t)row * DIM;
    u16x8 v0 = *(const u16x8*)(rp + lane * 8);
    u16x8 v1 = *(const u16x8*)(rp + 512 + lane * 8);
    float f[16];
    #pragma unroll
    for (int j = 0; j < 8; ++j) { f[j] = h2f(v0[j]); f[8 + j] = h2f(v1[j]); }
    float s = 0.f, sq = 0.f;
    #pragma unroll
    for (int j = 0; j < 16; ++j) { s += f[j]; sq += f[j] * f[j]; }
    #pragma unroll
    for (int m = 1; m < 64; m <<= 1) { s += __shfl_xor(s, m); sq += __shfl_xor(sq, m); }
    float mean = s * (1.0f / 1024.0f);
    float var = sq * (1.0f / 1024.0f) - mean * mean;
    float rstd = 1.0f / sqrtf(var + 1e-5f);
    u16x8 o0, o1;
    #pragma unroll
    for (int j = 0; j < 8; ++j) {
        int c0 = lane * 8 + j, c1 = 512 + lane * 8 + j;
        o0[j] = f2h((f[j] - mean) * rstd * g[c0] + b[c0]);
        o1[j] = f2h((f[8 + j] - mean) * rstd * g[c1] + b[c1]);
    }
    u16* op = out + (size_t)row * DIM;
    *(u16x8*)(op + lane * 8) = o0;
    *(u16x8*)(op + 512 + lane * 8) = o1;
}

extern "C" void kernel_launch(void* const* d_in, const int* in_sizes, int n_in,
                              void* d_out, int out_size, void* d_ws, size_t ws_size,
                              hipStream_t stream) {
    const float* x      = (const float*)d_in[0];
    const int*   wq     = (const int*)d_in[1];
    const float* scales = (const float*)d_in[2];
    const float* bias   = (const float*)d_in[3];
    const float* la     = (const float*)d_in[4];
    const float* lb     = (const float*)d_in[5];
    const float* gamma  = (const float*)d_in[6];
    const float* beta   = (const float*)d_in[7];

    char* ws = (char*)d_ws;
    u16* Weff = (u16*)ws;                                      // 37,748,736 B
    u16* actA = (u16*)(ws + (size_t)NLIN * DIM * DIM * 2);     // 67,108,864 B
    u16* actB = actA + (size_t)BATCH * DIM;                    // 67,108,864 B
    u16* dob  = (u16*)d_out;   // d_out doubles as fp16 scratch (134 MB total)
    float* dof = (float*)d_out;

    build_weff<<<dim3(64, 18), 256, 0, stream>>>(wq, scales, la, lb, Weff);
    xcast<<<(BATCH * DIM) / 2048, 256, 0, stream>>>(x, actA);

    int li = 0;
    for (int blk = 0; blk < 6; ++blk) {
        const u16* w0 = Weff + (size_t)(li + 0) * DIM * DIM;
        const u16* w1 = Weff + (size_t)(li + 1) * DIM * DIM;
        const u16* w2 = Weff + (size_t)(li + 2) * DIM * DIM;
        const float* b0 = bias + (li + 0) * DIM;
        const float* b1 = bias + (li + 1) * DIM;
        const float* b2 = bias + (li + 2) * DIM;
        if (blk < 5) {
            // X(actA) -> h1(actB) -> h2(d_out fp16) -> h3(actB) -> LN -> actA
            gemm256<0><<<512, 512, 0, stream>>>(actA, w0, b0, nullptr, actB);
            gemm256<0><<<512, 512, 0, stream>>>(actB, w1, b1, nullptr, dob);
            gemm256<1><<<512, 512, 0, stream>>>(dob,  w2, b2, actA, actB);
            ln_k<<<BATCH / 4, 256, 0, stream>>>(actB, gamma + blk * DIM, beta + blk * DIM, actA);
        } else {
            // final block: keep d_out free of live reads at the fp32 write
            gemm256<0><<<512, 512, 0, stream>>>(actA, w0, b0, nullptr, dob);
            gemm256<0><<<512, 512, 0, stream>>>(dob,  w1, b1, nullptr, actB);
            gemm256<2><<<512, 512, 0, stream>>>(actB, w2, b2, actA, (void*)dof);
        }
        li += 3;
    }
}

// Round 6
// 1420.546 us; speedup vs baseline: 2.3902x; 2.3902x over previous
//
#include <hip/hip_runtime.h>

typedef unsigned int u32;
typedef unsigned short u16;
typedef _Float16 f16;
typedef f16 f16x8 __attribute__((ext_vector_type(8)));
typedef float f32x4 __attribute__((ext_vector_type(4)));
typedef u16 u16x8 __attribute__((ext_vector_type(8)));

#define DIM 1024
#define BATCH 32768
#define RANK 32
#define NLIN 18

__device__ __forceinline__ u16 f2h(float f) {
    f16 h = (f16)f;
    return *(u16*)&h;
}
__device__ __forceinline__ float h2f(u16 u) {
    f16 h;
    *(u16*)&h = u;
    return (float)h;
}

__device__ __forceinline__ void gload16(const u16* g, u16* l) {
    __builtin_amdgcn_global_load_lds((__attribute__((address_space(1))) const void*)g,
                                     (__attribute__((address_space(3))) void*)l,
                                     16, 0, 0);
}

#define BAR()        __builtin_amdgcn_s_barrier()
#define SB0()        __builtin_amdgcn_sched_barrier(0)
#define ASM_VM0()    asm volatile("s_waitcnt vmcnt(0)" ::: "memory")
#define ASM_VM4()    asm volatile("s_waitcnt vmcnt(4)" ::: "memory")
#define ASM_LG0()    asm volatile("s_waitcnt lgkmcnt(0)" ::: "memory")

// ---- W_eff = dequant(wq, scales) + lb @ la  -> fp16 [NLIN][DIM][DIM] ----
__global__ __launch_bounds__(256) void build_weff(
    const int* __restrict__ wq, const float* __restrict__ scales,
    const float* __restrict__ la, const float* __restrict__ lb,
    u16* __restrict__ weff)
{
    int rb = blockIdx.x;   // 0..63, 16 rows each
    int li = blockIdx.y;   // 0..17
    int tid = threadIdx.x;
    int row0 = rb * 16;
    __shared__ float lb_s[16][RANK];
    __shared__ float la_s[RANK][256];
    for (int idx = tid; idx < 16 * RANK; idx += 256) {
        int o = idx >> 5, r = idx & 31;
        lb_s[o][r] = lb[((size_t)li * DIM + row0 + o) * RANK + r];
    }
    const int* wqL = wq + (size_t)li * DIM * DIM;
    const float* sL = scales + (size_t)li * (DIM * DIM / 16);
    u16* wout = weff + (size_t)li * DIM * DIM;
    for (int kc = 0; kc < DIM; kc += 256) {
        __syncthreads();
        #pragma unroll
        for (int j = 0; j < 32; ++j) {
            int idx = j * 256 + tid;
            int r = idx >> 8, c = idx & 255;
            la_s[r][c] = la[((size_t)li * RANK + r) * DIM + kc + c];
        }
        __syncthreads();
        int k = kc + tid;
        for (int o = 0; o < 16; ++o) {
            int og = row0 + o;
            float acc = ((float)wqL[og * DIM + k] - 8.0f) * sL[(og << 6) + (k >> 4)];
            #pragma unroll
            for (int r = 0; r < RANK; ++r)
                acc += lb_s[o][r] * la_s[r][tid];
            wout[og * DIM + k] = f2h(acc);
        }
    }
}

// ---- x fp32 -> fp16 ----
__global__ __launch_bounds__(256) void xcast(const float* __restrict__ x, u16* __restrict__ o) {
    size_t i = ((size_t)blockIdx.x * 256 + threadIdx.x) * 8;
    float4 a = *(const float4*)(x + i);
    float4 b = *(const float4*)(x + i + 4);
    u16x8 v;
    v[0] = f2h(a.x); v[1] = f2h(a.y); v[2] = f2h(a.z); v[3] = f2h(a.w);
    v[4] = f2h(b.x); v[5] = f2h(b.y); v[6] = f2h(b.z); v[7] = f2h(b.w);
    *(u16x8*)(o + i) = v;
}

// ---- 256x256x(BK=64) GEMM, 8 waves (2Mx4N), 2 phases/K-tile.
// Latency hiding with SINGLE fragment sets (no reg growth): each phase's
// ds_reads are issued BEFORE the phase-ending barrier (WAR vs issued MFMAs is
// HW-scoreboarded); consumer phase opens with bar+lgkmcnt(0), so read latency
// hides under other waves' MFMA backlog. Staging at t+2 distance; ledger:
// top-of-tile outstanding = [B(t+1):4, A(t+1):4]; ph0: +B(t+2), vmcnt(4)
// BEFORE bar (t+1 landed, globally visible after bar); ph1: read t+1 frags
// from other buffer, stage A(t+2). LDS 128 KiB, zero-conflict chunk-XOR
// swizzle (linear dest for global_load_lds; swizzle on global src + ds_read).
// EPI: 0 = relu(acc+bias)->fp16 ; 1 = acc+bias+res->fp16 ; 2 = acc+bias+res->fp32
template<int EPI>
__global__ __launch_bounds__(512, 2) void gemm256(
    const u16* __restrict__ X, const u16* __restrict__ W,
    const float* __restrict__ bias, const u16* __restrict__ res,
    void* __restrict__ outp)
{
    __shared__ __align__(16) u16 As[2][256 * 64];
    __shared__ __align__(16) u16 Bs[2][256 * 64];
    const int tid = threadIdx.x;
    const int bid = blockIdx.x;
    // XCD-bijective swizzle: 512 blocks, 8 XCDs, 64 contiguous wg per XCD
    const int wg = (bid & 7) * 64 + (bid >> 3);
    const int bm = wg >> 2;        // 0..127
    const int bn = wg & 3;         // 0..3
    const int wid = tid >> 6;
    const int lane = tid & 63;
    const int wm = wid >> 2;       // 0..1
    const int wn = wid & 3;        // 0..3

    // ---- staging source pointers (global side carries the swizzle) ----
    const int c1 = tid, c2 = tid + 512;           // chunk ids within a 1024-chunk half
    const int r1 = c1 >> 3, r2 = c2 >> 3;         // rows 0..127 within half
    const int l1 = ((c1 & 7) ^ (r1 & 7)) * 8;     // swizzled k-offset (u16)
    const int l2 = ((c2 & 7) ^ (r2 & 7)) * 8;
    const u16* gA0a = X + (size_t)(bm * 256 +       r1) * DIM + l1;
    const u16* gA0b = X + (size_t)(bm * 256 +       r2) * DIM + l2;
    const u16* gA1a = X + (size_t)(bm * 256 + 128 + r1) * DIM + l1;
    const u16* gA1b = X + (size_t)(bm * 256 + 128 + r2) * DIM + l2;
    const u16* gB0a = W + (size_t)(bn * 256 +       r1) * DIM + l1;
    const u16* gB0b = W + (size_t)(bn * 256 +       r2) * DIM + l2;
    const u16* gB1a = W + (size_t)(bn * 256 + 128 + r1) * DIM + l1;
    const u16* gB1b = W + (size_t)(bn * 256 + 128 + r2) * DIM + l2;
    const int d1 = c1 * 8, d2 = c2 * 8;           // linear LDS dest (u16), half adds 8192

    // ---- fragment read offsets ----
    const int kg = lane >> 4;
    const int sw = lane & 7;
    const int ch0 = ((0 * 4 + kg) ^ sw) * 8;      // ks=0 chunk (u16 offset in row)
    const int ch1 = ((1 * 4 + kg) ^ sw) * 8;      // ks=1
    const int aoff = (wm * 128 + (lane & 15)) * 64;
    const int boff = (wn * 64 + (lane & 15)) * 64;

    f32x4 acc[8][4];
    #pragma unroll
    for (int i = 0; i < 8; ++i)
        #pragma unroll
        for (int j = 0; j < 4; ++j)
            acc[i][j] = (f32x4){0.f, 0.f, 0.f, 0.f};
    f16x8 af[4][2];   // A fragments (one half at a time)
    f16x8 bf[4][2];   // B fragments (all 64 cols of this wave)

    // ---- prologue: stage t0 (A,B), then t1 (B FIRST, then A) ----
    gload16(gA0a, &As[0][d1]);        gload16(gA0b, &As[0][d2]);
    gload16(gA1a, &As[0][8192 + d1]); gload16(gA1b, &As[0][8192 + d2]);
    gload16(gB0a, &Bs[0][d1]);        gload16(gB0b, &Bs[0][d2]);
    gload16(gB1a, &Bs[0][8192 + d1]); gload16(gB1b, &Bs[0][8192 + d2]);
    gload16(gB0a + 64, &Bs[1][d1]);        gload16(gB0b + 64, &Bs[1][d2]);
    gload16(gB1a + 64, &Bs[1][8192 + d1]); gload16(gB1b + 64, &Bs[1][8192 + d2]);
    gload16(gA0a + 64, &As[1][d1]);        gload16(gA0b + 64, &As[1][d2]);
    gload16(gA1a + 64, &As[1][8192 + d1]); gload16(gA1b + 64, &As[1][8192 + d2]);

    #define RD_A(MH, BUF) { \
        _Pragma("unroll") \
        for (int fm = 0; fm < 4; ++fm) { \
            af[fm][0] = *(const f16x8*)&(BUF)[aoff + ((MH)*64 + fm*16)*64 + ch0]; \
            af[fm][1] = *(const f16x8*)&(BUF)[aoff + ((MH)*64 + fm*16)*64 + ch1]; \
        } }
    #define RD_B(BUF) { \
        _Pragma("unroll") \
        for (int fn = 0; fn < 4; ++fn) { \
            bf[fn][0] = *(const f16x8*)&(BUF)[boff + (fn*16)*64 + ch0]; \
            bf[fn][1] = *(const f16x8*)&(BUF)[boff + (fn*16)*64 + ch1]; \
        } }
    #define QUAD(MH, NH) { \
        __builtin_amdgcn_s_setprio(1); \
        _Pragma("unroll") \
        for (int ks = 0; ks < 2; ++ks) \
            _Pragma("unroll") \
            for (int fm = 0; fm < 4; ++fm) \
                _Pragma("unroll") \
                for (int fn = 0; fn < 2; ++fn) \
                    acc[(MH)*4+fm][(NH)*2+fn] = __builtin_amdgcn_mfma_f32_16x16x32_f16( \
                        af[fm][ks], bf[(NH)*2+fn][ks], acc[(MH)*4+fm][(NH)*2+fn], 0, 0, 0); \
        __builtin_amdgcn_s_setprio(0); }

    // wait t0's 8 loads (t1's 8 newer stay in flight); make globally visible
    asm volatile("s_waitcnt vmcnt(8)" ::: "memory");
    BAR();
    // pre-read tile0 ph0 fragments: A-half0 + B(all)
    RD_A(0, (&As[0][0]));
    RD_B((&Bs[0][0]));

    #pragma unroll 1
    for (int t = 0; t < 16; ++t) {
        const int p = t & 1;
        const u16* Ap = &As[p][0];
        u16* Awr = &As[p][0];          // t+2 shares this parity
        u16* Bwr = &Bs[p][0];
        const u16* An = &As[p ^ 1][0]; // t+1
        const u16* Bn = &Bs[p ^ 1][0];
        const int ko2 = (t + 2) * 64;
        // ---- ph0: M-half0 ----
        BAR();
        ASM_LG0(); SB0();
        QUAD(0, 0); QUAD(0, 1);        // af(h0,t), bf(t) — read pre-barrier
        RD_A(1, Ap);                   // af <- A-half1(t); WAR vs issued MFMAs: HW scoreboard
        if (t <= 13) {                 // B(t) LDS dead (its ds_reads were pre-ph0-bar)
            gload16(gB0a + ko2, &Bwr[d1]);        gload16(gB0b + ko2, &Bwr[d2]);
            gload16(gB1a + ko2, &Bwr[8192 + d1]); gload16(gB1b + ko2, &Bwr[8192 + d2]);
        }
        SB0();
        // outstanding: [B(t+1):4, A(t+1):4, B(t+2):4] -> vmcnt(4) waits t+1 fully
        if (t <= 13) ASM_VM4(); else if (t == 14) ASM_VM0();
        BAR();
        // ---- ph1: M-half1 ----
        ASM_LG0(); SB0();
        QUAD(1, 0); QUAD(1, 1);        // af(h1), bf
        if (t <= 14) {                 // t+1 staging landed & visible (vmcnt+bar above)
            RD_A(0, An);
            RD_B(Bn);
        }
        if (t <= 13) {                 // A(t) LDS dead (RD_A(1) completed at ph1 lgkm0)
            gload16(gA0a + ko2, &Awr[d1]);        gload16(gA0b + ko2, &Awr[d2]);
            gload16(gA1a + ko2, &Awr[8192 + d1]); gload16(gA1b + ko2, &Awr[8192 + d2]);
        }
        SB0();
    }

    // ---- epilogue: LDS transpose -> full-line vector stores ----
    ASM_LG0();
    BAR();                             // all waves done with As/Bs
    float* blk = (float*)&As[0][0] + wid * 1088;   // [16][68] f32 per wave
    const int mrow = bm * 256 + wm * 128;
    const int ncol = bn * 256 + wn * 64 + (lane & 7) * 8;
    float4 bv0 = *(const float4*)&bias[ncol];
    float4 bv1 = *(const float4*)&bias[ncol + 4];
    #pragma unroll
    for (int fm = 0; fm < 8; ++fm) {
        __builtin_amdgcn_sched_barrier(0);
        #pragma unroll
        for (int fn = 0; fn < 4; ++fn)
            #pragma unroll
            for (int reg = 0; reg < 4; ++reg)
                blk[((lane >> 4) * 4 + reg) * 68 + (lane & 15) + fn * 16] = acc[fm][fn][reg];
        ASM_LG0();
        __builtin_amdgcn_sched_barrier(0);
        #pragma unroll
        for (int pass = 0; pass < 2; ++pass) {
            const float* rp = &blk[(pass * 8 + (lane >> 3)) * 68 + (lane & 7) * 8];
            float4 v0 = *(const float4*)rp;
            float4 v1 = *(const float4*)(rp + 4);
            v0.x += bv0.x; v0.y += bv0.y; v0.z += bv0.z; v0.w += bv0.w;
            v1.x += bv1.x; v1.y += bv1.y; v1.z += bv1.z; v1.w += bv1.w;
            const int m = mrow + fm * 16 + pass * 8 + (lane >> 3);
            const size_t gi = (size_t)m * DIM + ncol;
            if (EPI == 0) {
                u16x8 o;
                o[0] = f2h(fmaxf(v0.x, 0.f)); o[1] = f2h(fmaxf(v0.y, 0.f));
                o[2] = f2h(fmaxf(v0.z, 0.f)); o[3] = f2h(fmaxf(v0.w, 0.f));
                o[4] = f2h(fmaxf(v1.x, 0.f)); o[5] = f2h(fmaxf(v1.y, 0.f));
                o[6] = f2h(fmaxf(v1.z, 0.f)); o[7] = f2h(fmaxf(v1.w, 0.f));
                *(u16x8*)((u16*)outp + gi) = o;
            } else {
                u16x8 rv = *(const u16x8*)(res + gi);
                v0.x += h2f(rv[0]); v0.y += h2f(rv[1]); v0.z += h2f(rv[2]); v0.w += h2f(rv[3]);
                v1.x += h2f(rv[4]); v1.y += h2f(rv[5]); v1.z += h2f(rv[6]); v1.w += h2f(rv[7]);
                if (EPI == 1) {
                    u16x8 o;
                    o[0] = f2h(v0.x); o[1] = f2h(v0.y); o[2] = f2h(v0.z); o[3] = f2h(v0.w);
                    o[4] = f2h(v1.x); o[5] = f2h(v1.y); o[6] = f2h(v1.z); o[7] = f2h(v1.w);
                    *(u16x8*)((u16*)outp + gi) = o;
                } else {
                    *(float4*)((float*)outp + gi) = v0;
                    *(float4*)((float*)outp + gi + 4) = v1;
                }
            }
        }
        ASM_LG0();
    }
    #undef RD_A
    #undef RD_B
    #undef QUAD
}

// ---- LayerNorm: fp16 in -> fp16 out, one wave per row ----
__global__ __launch_bounds__(256) void ln_k(const u16* __restrict__ in,
    const float* __restrict__ g, const float* __restrict__ b, u16* __restrict__ out)
{
    int row = blockIdx.x * 4 + (threadIdx.x >> 6);
    int lane = threadIdx.x & 63;
    const u16* rp = in + (size_t)row * DIM;
    u16x8 v0 = *(const u16x8*)(rp + lane * 8);
    u16x8 v1 = *(const u16x8*)(rp + 512 + lane * 8);
    float f[16];
    #pragma unroll
    for (int j = 0; j < 8; ++j) { f[j] = h2f(v0[j]); f[8 + j] = h2f(v1[j]); }
    float s = 0.f, sq = 0.f;
    #pragma unroll
    for (int j = 0; j < 16; ++j) { s += f[j]; sq += f[j] * f[j]; }
    #pragma unroll
    for (int m = 1; m < 64; m <<= 1) { s += __shfl_xor(s, m); sq += __shfl_xor(sq, m); }
    float mean = s * (1.0f / 1024.0f);
    float var = sq * (1.0f / 1024.0f) - mean * mean;
    float rstd = 1.0f / sqrtf(var + 1e-5f);
    u16x8 o0, o1;
    #pragma unroll
    for (int j = 0; j < 8; ++j) {
        int c0 = lane * 8 + j, c1 = 512 + lane * 8 + j;
        o0[j] = f2h((f[j] - mean) * rstd * g[c0] + b[c0]);
        o1[j] = f2h((f[8 + j] - mean) * rstd * g[c1] + b[c1]);
    }
    u16* op = out + (size_t)row * DIM;
    *(u16x8*)(op + lane * 8) = o0;
    *(u16x8*)(op + 512 + lane * 8) = o1;
}

extern "C" void kernel_launch(void* const* d_in, const int* in_sizes, int n_in,
                              void* d_out, int out_size, void* d_ws, size_t ws_size,
                              hipStream_t stream) {
    const float* x      = (const float*)d_in[0];
    const int*   wq     = (const int*)d_in[1];
    const float* scales = (const float*)d_in[2];
    const float* bias   = (const float*)d_in[3];
    const float* la     = (const float*)d_in[4];
    const float* lb     = (const float*)d_in[5];
    const float* gamma  = (const float*)d_in[6];
    const float* beta   = (const float*)d_in[7];

    char* ws = (char*)d_ws;
    u16* Weff = (u16*)ws;                                      // 37,748,736 B
    u16* actA = (u16*)(ws + (size_t)NLIN * DIM * DIM * 2);     // 67,108,864 B
    u16* actB = actA + (size_t)BATCH * DIM;                    // 67,108,864 B
    u16* dob  = (u16*)d_out;   // d_out doubles as fp16 scratch (134 MB total)
    float* dof = (float*)d_out;

    build_weff<<<dim3(64, 18), 256, 0, stream>>>(wq, scales, la, lb, Weff);
    xcast<<<(BATCH * DIM) / 2048, 256, 0, stream>>>(x, actA);

    int li = 0;
    for (int blk = 0; blk < 6; ++blk) {
        const u16* w0 = Weff + (size_t)(li + 0) * DIM * DIM;
        const u16* w1 = Weff + (size_t)(li + 1) * DIM * DIM;
        const u16* w2 = Weff + (size_t)(li + 2) * DIM * DIM;
        const float* b0 = bias + (li + 0) * DIM;
        const float* b1 = bias + (li + 1) * DIM;
        const float* b2 = bias + (li + 2) * DIM;
        if (blk < 5) {
            // X(actA) -> h1(actB) -> h2(d_out fp16) -> h3(actB) -> LN -> actA
            gemm256<0><<<512, 512, 0, stream>>>(actA, w0, b0, nullptr, actB);
            gemm256<0><<<512, 512, 0, stream>>>(actB, w1, b1, nullptr, dob);
            gemm256<1><<<512, 512, 0, stream>>>(dob,  w2, b2, actA, actB);
            ln_k<<<BATCH / 4, 256, 0, stream>>>(actB, gamma + blk * DIM, beta + blk * DIM, actA);
        } else {
            // final block: keep d_out free of live reads at the fp32 write
            gemm256<0><<<512, 512, 0, stream>>>(actA, w0, b0, nullptr, dob);
            gemm256<0><<<512, 512, 0, stream>>>(dob,  w1, b1, nullptr, actB);
            gemm256<2><<<512, 512, 0, stream>>>(actB, w2, b2, actA, (void*)dof);
        }
        li += 3;
    }
}